// Round 4
// baseline (371.024 us; speedup 1.0000x reference)
//
#include <hip/hip_runtime.h>

// Problem sizes: bs=2, T=8, H=W=128, dec=64, enc=32, nH=4, hh=ww=16
// x1 (2,64,8,64,64)  x2 (2,32,8,128,128)  attn (4,2,16,16,8,8)
// out (2,32,8,128,128) fp32

#define EPSV 1e-5f

typedef __attribute__((ext_vector_type(8))) short short8;
typedef __attribute__((ext_vector_type(4))) short short4v;
typedef __attribute__((ext_vector_type(4))) float floatx4;

__device__ inline short f2bf(float f) {
  union { float f; unsigned u; } v; v.f = f;
  unsigned r = (v.u + 0x7fffu + ((v.u >> 16) & 1u)) >> 16;
  return (short)r;
}
__device__ inline float bf2f(short s) {
  union { unsigned u; float f; } v; v.u = ((unsigned)(unsigned short)s) << 16;
  return v.f;
}

// ws layout (float offsets)
#define UB_OFF   0           // Ub bf16 CL 64ch: 8388608 floats
#define HMB_OFF  8388608     // HM raw bf16 CL 32ch: 4194304
#define HMN_OFF  12582912    // HM normalized
#define C1B_OFF  16777216    // C1 raw
#define C1N_OFF  20971520    // C1 normalized
#define C2B_OFF  25165824    // C2 raw
#define WB1_OFF  29360128    // 13824
#define WB2_OFF  29373952    // 4608
#define WUP_OFF  29378560    // 8192
#define ST_OFF   29386752    // 192
#define SC_OFF   29386944    // 192

// ---------------- prepack weights (conv B-fragments + upsample B-fragments)
__global__ __launch_bounds__(256) void k_repackb(const float* __restrict__ Wc1, const float* __restrict__ Wc2,
        const float* __restrict__ Wup,
        short* __restrict__ wb1, short* __restrict__ wb2, short* __restrict__ wupb) {
  int i = blockIdx.x*256 + threadIdx.x;
  if (i < 27648) {
    int cc = i / 9216, r = i % 9216;
    int tap = r / 1024, r2 = r % 1024;
    int nt = r2 >> 9, lane = (r2 >> 3) & 63, j = r2 & 7;
    int o = nt*16 + (lane & 15);
    int cin = cc*32 + (lane >> 4)*8 + j;
    wb1[i] = f2bf(Wc1[(o*96 + cin)*9 + tap]);
  }
  if (i < 9216) {
    int tap = i / 1024, r2 = i % 1024;
    int nt = r2 >> 9, lane = (r2 >> 3) & 63, j = r2 & 7;
    int o = nt*16 + (lane & 15);
    int cin = (lane >> 4)*8 + j;
    wb2[i] = f2bf(Wc2[(o*32 + cin)*9 + tap]);
  }
  if (i < 16384) {
    int j = i & 7, lane = (i >> 3) & 63, r = i >> 9;
    int nt = r & 3, kb = (r >> 2) & 1, p = r >> 3;
    int c = kb*32 + (lane >> 4)*8 + j;
    int o = nt*16 + (lane & 15);
    wupb[i] = f2bf(Wup[(c*64 + o)*4 + p]);
  }
}

// ---------------- upsample via MFMA (unchanged from R3)
__global__ __launch_bounds__(256) void k_up_mfma(const float* __restrict__ x1,
        const short* __restrict__ wupb, const float* __restrict__ bup,
        short* __restrict__ Ub) {
  __shared__ __align__(16) char smem[34816];
  short8* stage = (short8*)smem;
  int t = blockIdx.y, b = blockIdx.z;
  int chunk = blockIdx.x >> 2, parity = blockIdx.x & 3;
  int tid = threadIdx.x, lane = tid & 63, w = tid >> 6;

  {
    const float* xp = x1 + ((long)(b*64)*8 + t)*4096 + chunk*256 + tid;
    #pragma unroll
    for (int o8 = 0; o8 < 8; ++o8) {
      short8 v;
      #pragma unroll
      for (int j = 0; j < 8; ++j) v[j] = f2bf(xp[(long)(o8*8+j)*32768]);
      int kb = o8 >> 2, cq = o8 & 3;
      stage[(kb*16 + (tid>>4))*64 + cq*16 + (tid&15)] = v;
    }
  }
  __syncthreads();

  floatx4 acc[4][4];
  #pragma unroll
  for (int nt=0; nt<4; ++nt) {
    float bb = bup[nt*16 + (lane&15)];
    #pragma unroll
    for (int mt=0; mt<4; ++mt) acc[mt][nt] = (floatx4){bb,bb,bb,bb};
  }
  const short8* wp = (const short8*)wupb;
  #pragma unroll
  for (int kb=0; kb<2; ++kb) {
    short8 bfr[4];
    #pragma unroll
    for (int nt=0; nt<4; ++nt) bfr[nt] = wp[((parity*2+kb)*4+nt)*64 + lane];
    #pragma unroll
    for (int mt=0; mt<4; ++mt) {
      short8 a = stage[(kb*16 + w*4 + mt)*64 + lane];
      #pragma unroll
      for (int nt=0; nt<4; ++nt)
        acc[mt][nt] = __builtin_amdgcn_mfma_f32_16x16x32_bf16(a, bfr[nt], acc[mt][nt], 0,0,0);
    }
  }

  __syncthreads();
  short* trb = (short*)smem;
  #pragma unroll
  for (int mt=0; mt<4; ++mt)
    #pragma unroll
    for (int nt=0; nt<4; ++nt)
      #pragma unroll
      for (int r=0; r<4; ++r)
        trb[(w*64 + mt*16 + (lane>>4)*4 + r)*68 + nt*16 + (lane&15)] = f2bf(acc[mt][nt][r]);
  __syncthreads();

  int ip = chunk*256 + tid;
  int X = 2*(ip>>6) + (parity>>1), Y = 2*(ip&63) + (parity&1);
  short* dst = Ub + (((long)(b*8+t)*16384 + X*128 + Y)*64);
  const short* src = trb + tid*68;
  #pragma unroll
  for (int k=0; k<16; ++k)
    *(short4v*)(dst + k*4) = *(const short4v*)(src + k*4);
}

// ---------------- attention (bilinear-resized A) fused with 128->32 MLP -> HM raw + fused stats
__global__ __launch_bounds__(256) void k_ctxmlp(const float* __restrict__ x2,
        const float* __restrict__ attn, const float* __restrict__ Wmlp,
        const float* __restrict__ bmlp, short* __restrict__ HMb, float* __restrict__ st) {
  __shared__ float la[8448];                 // attn slice [n][ix][iy][s] 8192, reused as ps[256][33]
  __shared__ float sb[64];
  int t = blockIdx.y, b = blockIdx.z;
  int tid = threadIdx.x, lane = tid & 63;
  int pos = blockIdx.x*256 + tid;            // x*128+y
  if (tid < 64) sb[tid] = 0.f;
  float4* la4 = (float4*)la;
  const float4* g4 = (const float4*)attn;
  #pragma unroll
  for (int k=0;k<8;++k) {
    int i = k*256 + tid;                     // float4 index: (n,ix,iy,s4)
    int s4 = i & 1, iy = (i>>1)&15, ix = (i>>5)&15, n = i>>9;
    la4[i] = g4[((((n*2+b)*16+ix)*16+iy)*8+t)*2 + s4];
  }
  __syncthreads();
  int x = pos >> 7, y = pos & 127;
  float ux = (x+0.5f)*0.125f - 0.5f;
  float uy = (y+0.5f)*0.125f - 0.5f;
  int ix0 = (int)floorf(ux), iy0 = (int)floorf(uy);
  float fx = ux - (float)ix0, fy = uy - (float)iy0;
  int ixa = max(ix0,0), ixb = min(ix0+1,15);
  int iya = max(iy0,0), iyb = min(iy0+1,15);
  float w00=(1.f-fx)*(1.f-fy), w01=(1.f-fx)*fy, w10=fx*(1.f-fy), w11=fx*fy;
  float a[4][8];
  #pragma unroll
  for (int n=0;n<4;++n) {
    const float4* p00 = la4 + ((n*16+ixa)*16+iya)*2;
    const float4* p01 = la4 + ((n*16+ixa)*16+iyb)*2;
    const float4* p10 = la4 + ((n*16+ixb)*16+iya)*2;
    const float4* p11 = la4 + ((n*16+ixb)*16+iyb)*2;
    #pragma unroll
    for (int q=0;q<2;++q) {
      float4 c00=p00[q], c01=p01[q], c10=p10[q], c11=p11[q];
      a[n][q*4+0] = w00*c00.x + w01*c01.x + w10*c10.x + w11*c11.x;
      a[n][q*4+1] = w00*c00.y + w01*c01.y + w10*c10.y + w11*c11.y;
      a[n][q*4+2] = w00*c00.z + w01*c01.z + w10*c10.z + w11*c11.z;
      a[n][q*4+3] = w00*c00.w + w01*c01.w + w10*c10.w + w11*c11.w;
    }
  }
  float acc[32];
  #pragma unroll
  for (int o=0;o<32;++o) acc[o] = bmlp[o];
  const float* x2p = x2 + b*4194304 + pos;
  #pragma unroll 4
  for (int c=0;c<32;++c) {
    float xr[8];
    #pragma unroll
    for (int s=0;s<8;++s) xr[s] = x2p[(c*8+s)*16384];
    #pragma unroll
    for (int n=0;n<4;++n) {
      float ctx = 0.f;
      #pragma unroll
      for (int s=0;s<8;++s) ctx = fmaf(a[n][s], xr[s], ctx);
      const float* wrow = Wmlp + (c*4+n)*32;
      #pragma unroll
      for (int o=0;o<32;++o) acc[o] = fmaf(ctx, wrow[o], acc[o]);
    }
  }
  short8* hp = (short8*)(HMb + ((long)((b*8+t)*16384 + pos)) * 32);
  #pragma unroll
  for (int g=0; g<4; ++g) {
    short8 v;
    #pragma unroll
    for (int j=0;j<8;++j) v[j] = f2bf(acc[g*8+j]);
    hp[g] = v;
  }
  // fused per-channel stats: LDS transpose + column reduce
  __syncthreads();
  #pragma unroll
  for (int c=0;c<32;++c) la[tid*33 + c] = acc[c];
  __syncthreads();
  int ch = tid & 31, grp = tid >> 5;
  float s = 0.f, q = 0.f;
  #pragma unroll 8
  for (int p=0;p<32;++p) { float v = la[(grp*32+p)*33 + ch]; s += v; q += v*v; }
  s += __shfl_xor(s, 32); q += __shfl_xor(q, 32);
  if (lane < 32) { atomicAdd(&sb[ch], s); atomicAdd(&sb[32+ch], q); }
  __syncthreads();
  if (tid < 64) atomicAdd(&st[tid], sb[tid]);
}

__global__ void k_finalize(const float* __restrict__ st, const float* __restrict__ g,
                           const float* __restrict__ be, float* __restrict__ sc, float* __restrict__ sh) {
  int c = threadIdx.x;
  if (c < 32) {
    float mean = st[c] * (1.f/262144.f);
    float var  = st[32+c] * (1.f/262144.f) - mean*mean;
    float s = g[c] / sqrtf(var + EPSV);
    sc[c] = s;
    sh[c] = be[c] - mean*s;
  }
}

// ---------------- apply BN+ReLU on CL bf16 32-ch tensor: src -> dst
__global__ __launch_bounds__(256) void k_bnapply(const short* __restrict__ src,
        const float* __restrict__ sc, const float* __restrict__ sh, short* __restrict__ dst) {
  long i = (long)blockIdx.x*256 + threadIdx.x;   // position index, 262144 total
  const short8* sp = (const short8*)(src + i*32);
  short8* dp = (short8*)(dst + i*32);
  #pragma unroll
  for (int g=0; g<4; ++g) {
    short8 v = sp[g], o;
    #pragma unroll
    for (int j=0;j<8;++j)
      o[j] = f2bf(fmaxf(fmaf(bf2f(v[j]), sc[g*8+j], sh[g*8+j]), 0.f));
    dp[g] = o;
  }
}

// ---------------- 3x3 conv via direct-global bf16 MFMA implicit GEMM, fused output stats.
// chunk0: src0 (32ch CL, pre-normalized); chunks>=1: src1 (64ch CL raw), channels (cc-1)*32..
template<int NCHUNK>
__global__ __launch_bounds__(256) void k_convd(
    const short* __restrict__ src0, const short* __restrict__ src1,
    const short* __restrict__ wb, const float* __restrict__ bias,
    short* __restrict__ dstCL, float* __restrict__ st) {
  __shared__ __align__(16) short tr[256*32];   // epilogue transpose
  __shared__ float sbuf[64];
  int t = blockIdx.y, b = blockIdx.z;
  int tid = threadIdx.x, lane = tid & 63, w = tid >> 6;
  if (tid < 64) sbuf[tid] = 0.f;
  long slab = (long)(b*8+t)*16384;
  int pbase = blockIdx.x * 256;                // 2 full rows
  int x0 = pbase >> 7;
  int m = lane & 15, kg = lane >> 4;

  float bias0 = bias[m], bias1 = bias[16 + m];
  floatx4 acc[4][2];
  #pragma unroll
  for (int mt=0; mt<4; ++mt) {
    acc[mt][0] = (floatx4){bias0,bias0,bias0,bias0};
    acc[mt][1] = (floatx4){bias1,bias1,bias1,bias1};
  }

  #pragma unroll
  for (int cc=0; cc<NCHUNK; ++cc) {
    const short* sbase = (cc==0) ? src0 : src1;
    const int cstr = (cc==0) ? 32 : 64;
    const int coff = (cc==0) ? 0 : (cc-1)*32;
    const short8* wbp = (const short8*)wb + (long)cc*9*2*64;
    #pragma unroll
    for (int tap=0; tap<9; ++tap) {
      int dy = tap/3, dx = tap - 3*dy;
      short8 b0 = wbp[(tap*2+0)*64 + lane];
      short8 b1 = wbp[(tap*2+1)*64 + lane];
      #pragma unroll
      for (int mt=0; mt<4; ++mt) {
        int tile = w*4 + mt;                   // 0..15
        int row = x0 + (tile >> 3);
        int X = row + dy - 1;
        int Y = (tile & 7)*16 + m + dx - 1;
        short8 a = (short8)0;
        if (((unsigned)X < 128u) & ((unsigned)Y < 128u))
          a = *(const short8*)(sbase + (slab + X*128 + Y)*cstr + coff + kg*8);
        acc[mt][0] = __builtin_amdgcn_mfma_f32_16x16x32_bf16(a, b0, acc[mt][0], 0,0,0);
        acc[mt][1] = __builtin_amdgcn_mfma_f32_16x16x32_bf16(a, b1, acc[mt][1], 0,0,0);
      }
    }
  }

  // fused per-channel partial stats (channel = n = lane&15 within each ntile)
  float s0=0.f,q0=0.f,s1=0.f,q1=0.f;
  #pragma unroll
  for (int mt=0; mt<4; ++mt)
    #pragma unroll
    for (int r=0; r<4; ++r) {
      float v0 = acc[mt][0][r]; s0 += v0; q0 += v0*v0;
      float v1 = acc[mt][1][r]; s1 += v1; q1 += v1*v1;
    }
  s0 += __shfl_xor(s0,16); s0 += __shfl_xor(s0,32);
  q0 += __shfl_xor(q0,16); q0 += __shfl_xor(q0,32);
  s1 += __shfl_xor(s1,16); s1 += __shfl_xor(s1,32);
  q1 += __shfl_xor(q1,16); q1 += __shfl_xor(q1,32);
  if (lane < 16) {
    atomicAdd(&sbuf[lane],    s0); atomicAdd(&sbuf[16+lane], s1);
    atomicAdd(&sbuf[32+lane], q0); atomicAdd(&sbuf[48+lane], q1);
  }

  // transpose to [pos][ch] bf16 via LDS, coalesced CL store
  #pragma unroll
  for (int mt=0; mt<4; ++mt) {
    int tile = w*4 + mt;
    #pragma unroll
    for (int nt=0; nt<2; ++nt)
      #pragma unroll
      for (int r=0; r<4; ++r) {
        int pin = kg*4 + r;
        tr[(tile*16 + pin)*32 + nt*16 + m] = f2bf(acc[mt][nt][r]);
      }
  }
  __syncthreads();
  short8* d8 = (short8*)(dstCL + (slab + pbase + tid)*32);
  const short8* s8 = (const short8*)(tr + tid*32);
  d8[0]=s8[0]; d8[1]=s8[1]; d8[2]=s8[2]; d8[3]=s8[3];
  if (tid < 64) atomicAdd(&st[tid], sbuf[tid]);
}

// ---------------- final BN+ReLU: C2b (bf16 CL) -> out (fp32 planar)
__global__ __launch_bounds__(256) void k_bnrelu2(const short* __restrict__ C2b,
        const float* __restrict__ sc, const float* __restrict__ sh,
        float* __restrict__ out) {
  __shared__ float tb[10592];   // [ch][pos] at addr ch*321 + pos + (pos>>5)*8
  int t = blockIdx.y, b = blockIdx.z;
  int posbase = blockIdx.x * 256;
  int tid = threadIdx.x;
  long slab = (long)(b*8+t)*16384;
  {
    const short8* sp = (const short8*)(C2b + (slab + posbase + tid)*32);
    int pi = tid + (tid>>5)*8;
    #pragma unroll
    for (int g=0; g<4; ++g) {
      short8 v = sp[g];
      #pragma unroll
      for (int j=0; j<8; ++j) {
        int ch = g*8+j;
        tb[ch*321 + pi] = fmaxf(fmaf(bf2f(v[j]), sc[ch], sh[ch]), 0.f);
      }
    }
  }
  __syncthreads();
  int ch = tid >> 3, pg = tid & 7;
  float* op = out + ((long)(b*32+ch)*8 + t)*16384 + posbase + pg*32;
  const float* tp = tb + ch*321 + pg*40;
  #pragma unroll
  for (int k=0; k<8; ++k) {
    float4 v;
    v.x = tp[k*4+0]; v.y = tp[k*4+1]; v.z = tp[k*4+2]; v.w = tp[k*4+3];
    *(float4*)(op + k*4) = v;
  }
}

extern "C" void kernel_launch(void* const* d_in, const int* in_sizes, int n_in,
                              void* d_out, int out_size, void* d_ws, size_t ws_size,
                              hipStream_t stream) {
  (void)in_sizes; (void)n_in; (void)out_size; (void)ws_size;
  const float* x1   = (const float*)d_in[0];
  const float* x2   = (const float*)d_in[1];
  const float* attn = (const float*)d_in[2];
  const float* Wup  = (const float*)d_in[3];
  const float* bup  = (const float*)d_in[4];
  const float* Wmlp = (const float*)d_in[5];
  const float* bmlp = (const float*)d_in[6];
  const float* gmlp = (const float*)d_in[7];
  const float* bemlp= (const float*)d_in[8];
  const float* Wc1  = (const float*)d_in[9];
  const float* bc1  = (const float*)d_in[10];
  const float* gc1  = (const float*)d_in[11];
  const float* bec1 = (const float*)d_in[12];
  const float* Wc2  = (const float*)d_in[13];
  const float* bc2  = (const float*)d_in[14];
  const float* gc2  = (const float*)d_in[15];
  const float* bec2 = (const float*)d_in[16];
  float* ws  = (float*)d_ws;
  float* out = (float*)d_out;

  short* Ub   = (short*)(ws + UB_OFF);
  short* HMb  = (short*)(ws + HMB_OFF);
  short* HMn  = (short*)(ws + HMN_OFF);
  short* C1b  = (short*)(ws + C1B_OFF);
  short* C1n  = (short*)(ws + C1N_OFF);
  short* C2b  = (short*)(ws + C2B_OFF);
  short* wb1  = (short*)(ws + WB1_OFF);
  short* wb2  = (short*)(ws + WB2_OFF);
  short* wupb = (short*)(ws + WUP_OFF);
  float* st1  = ws + ST_OFF;
  float* st2  = st1 + 64;
  float* st3  = st2 + 64;
  float* sc1  = ws + SC_OFF;  float* sh1 = sc1+32;
  float* sc2  = sh1+32;       float* sh2 = sc2+32;
  float* sc3  = sh2+32;       float* sh3 = sc3+32;

  hipMemsetAsync(st1, 0, 192*sizeof(float), stream);
  k_repackb<<<108, 256, 0, stream>>>(Wc1, Wc2, Wup, wb1, wb2, wupb);
  k_up_mfma<<<dim3(64,8,2), 256, 0, stream>>>(x1, wupb, bup, Ub);
  k_ctxmlp<<<dim3(64,8,2), 256, 0, stream>>>(x2, attn, Wmlp, bmlp, HMb, st1);
  k_finalize<<<1, 32, 0, stream>>>(st1, gmlp, bemlp, sc1, sh1);
  k_bnapply<<<1024, 256, 0, stream>>>(HMb, sc1, sh1, HMn);
  k_convd<3><<<dim3(64,8,2), 256, 0, stream>>>(HMn, Ub, wb1, bc1, C1b, st2);
  k_finalize<<<1, 32, 0, stream>>>(st2, gc1, bec1, sc2, sh2);
  k_bnapply<<<1024, 256, 0, stream>>>(C1b, sc2, sh2, C1n);
  k_convd<1><<<dim3(64,8,2), 256, 0, stream>>>(C1n, nullptr, wb2, bc2, C2b, st3);
  k_finalize<<<1, 32, 0, stream>>>(st3, gc2, bec2, sc3, sh3);
  k_bnrelu2<<<dim3(64,8,2), 256, 0, stream>>>(C2b, sc3, sh3, out);
}

// Round 5
// 323.591 us; speedup vs baseline: 1.1466x; 1.1466x over previous
//
#include <hip/hip_runtime.h>

// Problem sizes: bs=2, T=8, H=W=128, dec=64, enc=32, nH=4, hh=ww=16
// x1 (2,64,8,64,64)  x2 (2,32,8,128,128)  attn (4,2,16,16,8,8)
// out (2,32,8,128,128) fp32

#define EPSV 1e-5f

typedef __attribute__((ext_vector_type(8))) short short8;
typedef __attribute__((ext_vector_type(4))) short short4v;
typedef __attribute__((ext_vector_type(4))) float floatx4;

__device__ inline short f2bf(float f) {
  union { float f; unsigned u; } v; v.f = f;
  unsigned r = (v.u + 0x7fffu + ((v.u >> 16) & 1u)) >> 16;
  return (short)r;
}
__device__ inline float bf2f(short s) {
  union { unsigned u; float f; } v; v.u = ((unsigned)(unsigned short)s) << 16;
  return v.f;
}

// ws layout (float offsets)
#define UB_OFF   0           // Ub bf16 CL 64ch: 8388608 floats
#define HMB_OFF  8388608     // HM raw bf16 CL 32ch
#define C1B_OFF  12582912    // C1 raw bf16 CL
#define C2B_OFF  16777216    // C2 raw bf16 CL
#define X2B_OFF  20971520    // x2 bf16 planar
#define WB1_OFF  25165824    // 13824
#define WB2_OFF  25179648    // 4608
#define WUP_OFF  25184256    // 8192
#define ST_OFF   25192448    // 192
#define SC_OFF   25192640    // 192

// ---------------- prepack weights (conv B-fragments + upsample B-fragments)
__global__ __launch_bounds__(256) void k_repackb(const float* __restrict__ Wc1, const float* __restrict__ Wc2,
        const float* __restrict__ Wup,
        short* __restrict__ wb1, short* __restrict__ wb2, short* __restrict__ wupb) {
  int i = blockIdx.x*256 + threadIdx.x;
  if (i < 27648) {
    int cc = i / 9216, r = i % 9216;
    int tap = r / 1024, r2 = r % 1024;
    int nt = r2 >> 9, lane = (r2 >> 3) & 63, j = r2 & 7;
    int o = nt*16 + (lane & 15);
    int cin = cc*32 + (lane >> 4)*8 + j;
    wb1[i] = f2bf(Wc1[(o*96 + cin)*9 + tap]);
  }
  if (i < 9216) {
    int tap = i / 1024, r2 = i % 1024;
    int nt = r2 >> 9, lane = (r2 >> 3) & 63, j = r2 & 7;
    int o = nt*16 + (lane & 15);
    int cin = (lane >> 4)*8 + j;
    wb2[i] = f2bf(Wc2[(o*32 + cin)*9 + tap]);
  }
  if (i < 16384) {
    int j = i & 7, lane = (i >> 3) & 63, r = i >> 9;
    int nt = r & 3, kb = (r >> 2) & 1, p = r >> 3;
    int c = kb*32 + (lane >> 4)*8 + j;
    int o = nt*16 + (lane & 15);
    wupb[i] = f2bf(Wup[(c*64 + o)*4 + p]);
  }
}

// ---------------- x2 fp32 -> bf16 (planar, same layout)
__global__ __launch_bounds__(256) void k_x2b(const float* __restrict__ x2, short* __restrict__ x2b) {
  long i = ((long)blockIdx.x*256 + threadIdx.x)*4;
  float4 v = *(const float4*)(x2 + i);
  short4v o;
  o[0]=f2bf(v.x); o[1]=f2bf(v.y); o[2]=f2bf(v.z); o[3]=f2bf(v.w);
  *(short4v*)(x2b + i) = o;
}

// ---------------- upsample via MFMA
__global__ __launch_bounds__(256) void k_up_mfma(const float* __restrict__ x1,
        const short* __restrict__ wupb, const float* __restrict__ bup,
        short* __restrict__ Ub) {
  __shared__ __align__(16) char smem[34816];
  short8* stage = (short8*)smem;
  int t = blockIdx.y, b = blockIdx.z;
  int chunk = blockIdx.x >> 2, parity = blockIdx.x & 3;
  int tid = threadIdx.x, lane = tid & 63, w = tid >> 6;

  {
    const float* xp = x1 + ((long)(b*64)*8 + t)*4096 + chunk*256 + tid;
    #pragma unroll
    for (int o8 = 0; o8 < 8; ++o8) {
      short8 v;
      #pragma unroll
      for (int j = 0; j < 8; ++j) v[j] = f2bf(xp[(long)(o8*8+j)*32768]);
      int kb = o8 >> 2, cq = o8 & 3;
      stage[(kb*16 + (tid>>4))*64 + cq*16 + (tid&15)] = v;
    }
  }
  __syncthreads();

  floatx4 acc[4][4];
  #pragma unroll
  for (int nt=0; nt<4; ++nt) {
    float bb = bup[nt*16 + (lane&15)];
    #pragma unroll
    for (int mt=0; mt<4; ++mt) acc[mt][nt] = (floatx4){bb,bb,bb,bb};
  }
  const short8* wp = (const short8*)wupb;
  #pragma unroll
  for (int kb=0; kb<2; ++kb) {
    short8 bfr[4];
    #pragma unroll
    for (int nt=0; nt<4; ++nt) bfr[nt] = wp[((parity*2+kb)*4+nt)*64 + lane];
    #pragma unroll
    for (int mt=0; mt<4; ++mt) {
      short8 a = stage[(kb*16 + w*4 + mt)*64 + lane];
      #pragma unroll
      for (int nt=0; nt<4; ++nt)
        acc[mt][nt] = __builtin_amdgcn_mfma_f32_16x16x32_bf16(a, bfr[nt], acc[mt][nt], 0,0,0);
    }
  }

  __syncthreads();
  short* trb = (short*)smem;
  #pragma unroll
  for (int mt=0; mt<4; ++mt)
    #pragma unroll
    for (int nt=0; nt<4; ++nt)
      #pragma unroll
      for (int r=0; r<4; ++r)
        trb[(w*64 + mt*16 + (lane>>4)*4 + r)*68 + nt*16 + (lane&15)] = f2bf(acc[mt][nt][r]);
  __syncthreads();

  int ip = chunk*256 + tid;
  int X = 2*(ip>>6) + (parity>>1), Y = 2*(ip&63) + (parity&1);
  short* dst = Ub + (((long)(b*8+t)*16384 + X*128 + Y)*64);
  const short* src = trb + tid*68;
  #pragma unroll
  for (int k=0; k<16; ++k)
    *(short4v*)(dst + k*4) = *(const short4v*)(src + k*4);
}

// ---------------- attention (bilinear-resized A) fused with 128->32 MLP -> HM raw + fused stats
__global__ __launch_bounds__(256) void k_ctxmlp(const short* __restrict__ x2b,
        const float* __restrict__ attn, const float* __restrict__ Wmlp,
        const float* __restrict__ bmlp, short* __restrict__ HMb, float* __restrict__ st) {
  __shared__ float la[8448];                 // attn slice [n][ix][iy][s] 8192, reused as ps[256][33]
  __shared__ float sb[64];
  int t = blockIdx.y, b = blockIdx.z;
  int tid = threadIdx.x, lane = tid & 63;
  int pos = blockIdx.x*256 + tid;            // x*128+y
  if (tid < 64) sb[tid] = 0.f;
  float4* la4 = (float4*)la;
  const float4* g4 = (const float4*)attn;
  #pragma unroll
  for (int k=0;k<8;++k) {
    int i = k*256 + tid;                     // float4 index: (n,ix,iy,s4)
    int s4 = i & 1, iy = (i>>1)&15, ix = (i>>5)&15, n = i>>9;
    la4[i] = g4[((((n*2+b)*16+ix)*16+iy)*8+t)*2 + s4];
  }
  __syncthreads();
  int x = pos >> 7, y = pos & 127;
  float ux = (x+0.5f)*0.125f - 0.5f;
  float uy = (y+0.5f)*0.125f - 0.5f;
  int ix0 = (int)floorf(ux), iy0 = (int)floorf(uy);
  float fx = ux - (float)ix0, fy = uy - (float)iy0;
  int ixa = max(ix0,0), ixb = min(ix0+1,15);
  int iya = max(iy0,0), iyb = min(iy0+1,15);
  float w00=(1.f-fx)*(1.f-fy), w01=(1.f-fx)*fy, w10=fx*(1.f-fy), w11=fx*fy;
  float a[4][8];
  #pragma unroll
  for (int n=0;n<4;++n) {
    const float4* p00 = la4 + ((n*16+ixa)*16+iya)*2;
    const float4* p01 = la4 + ((n*16+ixa)*16+iyb)*2;
    const float4* p10 = la4 + ((n*16+ixb)*16+iya)*2;
    const float4* p11 = la4 + ((n*16+ixb)*16+iyb)*2;
    #pragma unroll
    for (int q=0;q<2;++q) {
      float4 c00=p00[q], c01=p01[q], c10=p10[q], c11=p11[q];
      a[n][q*4+0] = w00*c00.x + w01*c01.x + w10*c10.x + w11*c11.x;
      a[n][q*4+1] = w00*c00.y + w01*c01.y + w10*c10.y + w11*c11.y;
      a[n][q*4+2] = w00*c00.z + w01*c01.z + w10*c10.z + w11*c11.z;
      a[n][q*4+3] = w00*c00.w + w01*c01.w + w10*c10.w + w11*c11.w;
    }
  }
  float acc[32];
  #pragma unroll
  for (int o=0;o<32;++o) acc[o] = bmlp[o];
  const short* x2p = x2b + (long)b*4194304 + pos;
  #pragma unroll 4
  for (int c=0;c<32;++c) {
    float xr[8];
    #pragma unroll
    for (int s=0;s<8;++s) xr[s] = bf2f(x2p[(long)(c*8+s)*16384]);
    #pragma unroll
    for (int n=0;n<4;++n) {
      float ctx = 0.f;
      #pragma unroll
      for (int s=0;s<8;++s) ctx = fmaf(a[n][s], xr[s], ctx);
      const float* wrow = Wmlp + (c*4+n)*32;
      #pragma unroll
      for (int o=0;o<32;++o) acc[o] = fmaf(ctx, wrow[o], acc[o]);
    }
  }
  short8* hp = (short8*)(HMb + ((long)((b*8+t)*16384 + pos)) * 32);
  #pragma unroll
  for (int g=0; g<4; ++g) {
    short8 v;
    #pragma unroll
    for (int j=0;j<8;++j) v[j] = f2bf(acc[g*8+j]);
    hp[g] = v;
  }
  // fused per-channel stats: LDS transpose + column reduce
  __syncthreads();
  #pragma unroll
  for (int c=0;c<32;++c) la[tid*33 + c] = acc[c];
  __syncthreads();
  int ch = tid & 31, grp = tid >> 5;
  float s = 0.f, q = 0.f;
  #pragma unroll 8
  for (int p=0;p<32;++p) { float v = la[(grp*32+p)*33 + ch]; s += v; q += v*v; }
  s += __shfl_xor(s, 32); q += __shfl_xor(q, 32);
  if (lane < 32) { atomicAdd(&sb[ch], s); atomicAdd(&sb[32+ch], q); }
  __syncthreads();
  if (tid < 64) atomicAdd(&st[tid], sb[tid]);
}

__global__ void k_finalize(const float* __restrict__ st, const float* __restrict__ g,
                           const float* __restrict__ be, float* __restrict__ sc, float* __restrict__ sh) {
  int c = threadIdx.x;
  if (c < 32) {
    float mean = st[c] * (1.f/262144.f);
    float var  = st[32+c] * (1.f/262144.f) - mean*mean;
    float s = g[c] / sqrtf(var + EPSV);
    sc[c] = s;
    sh[c] = be[c] - mean*s;
  }
}

// ---------------- 3x3 conv via bf16 MFMA implicit GEMM, reg->LDS double-buffered K-chunks.
// chunk0 = BN+ReLU(src0, sc/sh) (32ch CL raw in); chunks>=1 = srcU (64ch CL raw), channels (cc-1)*32..
template<int NCHUNK>
__global__ __launch_bounds__(256) void k_convp(
    const short* __restrict__ src0, const short* __restrict__ srcU,
    const short* __restrict__ wb, const float* __restrict__ bias,
    const float* __restrict__ sc, const float* __restrict__ sh,
    short* __restrict__ dstCL, float* __restrict__ st) {
  constexpr int NBUF = (NCHUNK > 1) ? 2 : 1;
  __shared__ __align__(16) short stage[NBUF][324*40];
  __shared__ float sbuf[64];
  int t = blockIdx.y, b = blockIdx.z;
  int tid = threadIdx.x, lane = tid & 63, w = tid >> 6;
  if (tid < 64) sbuf[tid] = 0.f;
  long slab = (long)(b*8+t)*16384;
  int x0 = (int)(blockIdx.x >> 3) * 16, y0 = (int)(blockIdx.x & 7) * 16;
  int m = lane & 15, kg = lane >> 4;

  // staging geometry: this thread owns positions pA=tid and pB=tid+256 (if <324)
  int pA = tid;        int rA = pA/18, cA = pA - rA*18;
  int XA = x0-1+rA, YA = y0-1+cA;
  bool okA = ((unsigned)XA < 128u) & ((unsigned)YA < 128u);
  int pB = tid + 256;  bool hasB = pB < 324;
  int rB = pB/18, cB = pB - rB*18;
  int XB = x0-1+rB, YB = y0-1+cB;
  bool okB = hasB && (((unsigned)XB < 128u) & ((unsigned)YB < 128u));
  long offA = slab + XA*128 + YA, offB = slab + XB*128 + YB;

  short8 preA[4], preB[4];

  float bias0 = bias[m], bias1 = bias[16 + m];
  floatx4 acc[4][2];
  #pragma unroll
  for (int mt=0; mt<4; ++mt) {
    acc[mt][0] = (floatx4){bias0,bias0,bias0,bias0};
    acc[mt][1] = (floatx4){bias1,bias1,bias1,bias1};
  }

  // ---- prefetch chunk0 (raw), BN applied at write time
  {
    const short* sA = src0 + offA*32;
    const short* sB = src0 + offB*32;
    #pragma unroll
    for (int g=0; g<4; ++g) {
      preA[g] = okA ? *(const short8*)(sA + g*8) : (short8)0;
      preB[g] = okB ? *(const short8*)(sB + g*8) : (short8)0;
    }
  }
  // write chunk0 with BN+ReLU (padding stays exact zero)
  #pragma unroll
  for (int g=0; g<4; ++g) {
    short8 vA, vB;
    #pragma unroll
    for (int j=0;j<8;++j) {
      int ch = g*8+j;
      float scv = sc[ch], shv = sh[ch];
      vA[j] = okA ? f2bf(fmaxf(fmaf(bf2f(preA[g][j]), scv, shv), 0.f)) : (short)0;
      vB[j] = okB ? f2bf(fmaxf(fmaf(bf2f(preB[g][j]), scv, shv), 0.f)) : (short)0;
    }
    *(short8*)(&stage[0][pA*40 + g*8]) = vA;
    if (hasB) *(short8*)(&stage[0][pB*40 + g*8]) = vB;
  }
  __syncthreads();

  const short8* wbp = (const short8*)wb;
  #pragma unroll
  for (int cc=0; cc<NCHUNK; ++cc) {
    // prefetch next chunk (U channels) into registers — overlaps with MFMAs below
    if (cc+1 < NCHUNK) {
      int coff = cc*32;   // (cc+1)-1 = cc
      const short* sA = srcU + offA*64 + coff;
      const short* sB = srcU + offB*64 + coff;
      #pragma unroll
      for (int g=0; g<4; ++g) {
        preA[g] = okA ? *(const short8*)(sA + g*8) : (short8)0;
        preB[g] = okB ? *(const short8*)(sB + g*8) : (short8)0;
      }
    }
    // MFMAs on current buffer
    #pragma unroll
    for (int tap=0; tap<9; ++tap) {
      int dy = tap/3, dx = tap - 3*dy;
      short8 b0 = wbp[((cc*9+tap)*2+0)*64 + lane];
      short8 b1 = wbp[((cc*9+tap)*2+1)*64 + lane];
      #pragma unroll
      for (int mt=0; mt<4; ++mt) {
        int p = (w*4 + mt + dy)*18 + m + dx;
        short8 a = *(const short8*)(&stage[cc & (NBUF-1)][p*40 + kg*8]);
        acc[mt][0] = __builtin_amdgcn_mfma_f32_16x16x32_bf16(a, b0, acc[mt][0], 0,0,0);
        acc[mt][1] = __builtin_amdgcn_mfma_f32_16x16x32_bf16(a, b1, acc[mt][1], 0,0,0);
      }
    }
    // drain prefetched regs into the other buffer (vmcnt wait lands here, after MFMAs)
    if (cc+1 < NCHUNK) {
      #pragma unroll
      for (int g=0; g<4; ++g) {
        *(short8*)(&stage[(cc+1) & (NBUF-1)][pA*40 + g*8]) = preA[g];
        if (hasB) *(short8*)(&stage[(cc+1) & (NBUF-1)][pB*40 + g*8]) = preB[g];
      }
    }
    __syncthreads();
  }

  // fused per-channel partial stats
  float s0=0.f,q0=0.f,s1=0.f,q1=0.f;
  #pragma unroll
  for (int mt=0; mt<4; ++mt)
    #pragma unroll
    for (int r=0; r<4; ++r) {
      float v0 = acc[mt][0][r]; s0 += v0; q0 += v0*v0;
      float v1 = acc[mt][1][r]; s1 += v1; q1 += v1*v1;
    }
  s0 += __shfl_xor(s0,16); s0 += __shfl_xor(s0,32);
  q0 += __shfl_xor(q0,16); q0 += __shfl_xor(q0,32);
  s1 += __shfl_xor(s1,16); s1 += __shfl_xor(s1,32);
  q1 += __shfl_xor(q1,16); q1 += __shfl_xor(q1,32);
  if (lane < 16) {
    atomicAdd(&sbuf[lane],    s0); atomicAdd(&sbuf[16+lane], s1);
    atomicAdd(&sbuf[32+lane], q0); atomicAdd(&sbuf[48+lane], q1);
  }

  // transpose to [pos][ch] bf16 via LDS (reuse stage[0]), coalesced CL store
  short* tr = &stage[0][0];
  #pragma unroll
  for (int mt=0; mt<4; ++mt) {
    int tile = w*4 + mt;
    #pragma unroll
    for (int nt=0; nt<2; ++nt)
      #pragma unroll
      for (int r=0; r<4; ++r) {
        int pin = kg*4 + r;
        tr[(tile*16 + pin)*32 + nt*16 + m] = f2bf(acc[mt][nt][r]);
      }
  }
  __syncthreads();
  int px = tid >> 4, py = tid & 15;
  short8* d8 = (short8*)(dstCL + ((slab + (long)(x0+px)*128 + (y0+py))*32));
  const short8* s8 = (const short8*)(tr + tid*32);
  d8[0]=s8[0]; d8[1]=s8[1]; d8[2]=s8[2]; d8[3]=s8[3];
  if (tid < 64) atomicAdd(&st[tid], sbuf[tid]);
}

// ---------------- final BN+ReLU: C2b (bf16 CL) -> out (fp32 planar)
__global__ __launch_bounds__(256) void k_bnrelu2(const short* __restrict__ C2b,
        const float* __restrict__ sc, const float* __restrict__ sh,
        float* __restrict__ out) {
  __shared__ float tb[10592];   // [ch][pos] at addr ch*321 + pos + (pos>>5)*8
  int t = blockIdx.y, b = blockIdx.z;
  int posbase = blockIdx.x * 256;
  int tid = threadIdx.x;
  long slab = (long)(b*8+t)*16384;
  {
    const short8* sp = (const short8*)(C2b + (slab + posbase + tid)*32);
    int pi = tid + (tid>>5)*8;
    #pragma unroll
    for (int g=0; g<4; ++g) {
      short8 v = sp[g];
      #pragma unroll
      for (int j=0; j<8; ++j) {
        int ch = g*8+j;
        tb[ch*321 + pi] = fmaxf(fmaf(bf2f(v[j]), sc[ch], sh[ch]), 0.f);
      }
    }
  }
  __syncthreads();
  int ch = tid >> 3, pg = tid & 7;
  float* op = out + ((long)(b*32+ch)*8 + t)*16384 + posbase + pg*32;
  const float* tp = tb + ch*321 + pg*40;
  #pragma unroll
  for (int k=0; k<8; ++k) {
    float4 v;
    v.x = tp[k*4+0]; v.y = tp[k*4+1]; v.z = tp[k*4+2]; v.w = tp[k*4+3];
    *(float4*)(op + k*4) = v;
  }
}

extern "C" void kernel_launch(void* const* d_in, const int* in_sizes, int n_in,
                              void* d_out, int out_size, void* d_ws, size_t ws_size,
                              hipStream_t stream) {
  (void)in_sizes; (void)n_in; (void)out_size; (void)ws_size;
  const float* x1   = (const float*)d_in[0];
  const float* x2   = (const float*)d_in[1];
  const float* attn = (const float*)d_in[2];
  const float* Wup  = (const float*)d_in[3];
  const float* bup  = (const float*)d_in[4];
  const float* Wmlp = (const float*)d_in[5];
  const float* bmlp = (const float*)d_in[6];
  const float* gmlp = (const float*)d_in[7];
  const float* bemlp= (const float*)d_in[8];
  const float* Wc1  = (const float*)d_in[9];
  const float* bc1  = (const float*)d_in[10];
  const float* gc1  = (const float*)d_in[11];
  const float* bec1 = (const float*)d_in[12];
  const float* Wc2  = (const float*)d_in[13];
  const float* bc2  = (const float*)d_in[14];
  const float* gc2  = (const float*)d_in[15];
  const float* bec2 = (const float*)d_in[16];
  float* ws  = (float*)d_ws;
  float* out = (float*)d_out;

  short* Ub   = (short*)(ws + UB_OFF);
  short* HMb  = (short*)(ws + HMB_OFF);
  short* C1b  = (short*)(ws + C1B_OFF);
  short* C2b  = (short*)(ws + C2B_OFF);
  short* x2b  = (short*)(ws + X2B_OFF);
  short* wb1  = (short*)(ws + WB1_OFF);
  short* wb2  = (short*)(ws + WB2_OFF);
  short* wupb = (short*)(ws + WUP_OFF);
  float* st1  = ws + ST_OFF;
  float* st2  = st1 + 64;
  float* st3  = st2 + 64;
  float* sc1  = ws + SC_OFF;  float* sh1 = sc1+32;
  float* sc2  = sh1+32;       float* sh2 = sc2+32;
  float* sc3  = sh2+32;       float* sh3 = sc3+32;

  hipMemsetAsync(st1, 0, 192*sizeof(float), stream);
  k_repackb<<<108, 256, 0, stream>>>(Wc1, Wc2, Wup, wb1, wb2, wupb);
  k_x2b<<<8192, 256, 0, stream>>>(x2, x2b);
  k_up_mfma<<<dim3(64,8,2), 256, 0, stream>>>(x1, wupb, bup, Ub);
  k_ctxmlp<<<dim3(64,8,2), 256, 0, stream>>>(x2b, attn, Wmlp, bmlp, HMb, st1);
  k_finalize<<<1, 32, 0, stream>>>(st1, gmlp, bemlp, sc1, sh1);
  k_convp<3><<<dim3(64,8,2), 256, 0, stream>>>(HMb, Ub, wb1, bc1, sc1, sh1, C1b, st2);
  k_finalize<<<1, 32, 0, stream>>>(st2, gc1, bec1, sc2, sh2);
  k_convp<1><<<dim3(64,8,2), 256, 0, stream>>>(C1b, nullptr, wb2, bc2, sc2, sh2, C2b, st3);
  k_finalize<<<1, 32, 0, stream>>>(st3, gc2, bec2, sc3, sh3);
  k_bnrelu2<<<dim3(64,8,2), 256, 0, stream>>>(C2b, sc3, sh3, out);
}

// Round 6
// 308.043 us; speedup vs baseline: 1.2045x; 1.0505x over previous
//
#include <hip/hip_runtime.h>

// Problem sizes: bs=2, T=8, H=W=128, dec=64, enc=32, nH=4, hh=ww=16
// x1 (2,64,8,64,64)  x2 (2,32,8,128,128)  attn (4,2,16,16,8,8)
// out (2,32,8,128,128) fp32

#define EPSV 1e-5f

typedef __attribute__((ext_vector_type(8))) short short8;
typedef __attribute__((ext_vector_type(4))) short short4v;
typedef __attribute__((ext_vector_type(4))) float floatx4;

__device__ inline short f2bf(float f) {
  union { float f; unsigned u; } v; v.f = f;
  unsigned r = (v.u + 0x7fffu + ((v.u >> 16) & 1u)) >> 16;
  return (short)r;
}
__device__ inline float bf2f(short s) {
  union { unsigned u; float f; } v; v.u = ((unsigned)(unsigned short)s) << 16;
  return v.f;
}

// ws layout (float offsets)
#define UB_OFF   0           // Ub bf16 CL 64ch
#define HMB_OFF  8388608     // HM raw bf16 CL 32ch
#define C1B_OFF  12582912
#define C2B_OFF  16777216
#define X2T_OFF  20971520    // x2 bf16 [b][s][pos][c]
#define WB1_OFF  29360128    // 13824 floats
#define WB2_OFF  29373952    // 4608
#define WUP_OFF  29378560    // 8192
#define WMB_OFF  29386752    // 2048
#define ST_OFF   29388800    // 192
#define SC_OFF   29388992    // 192

// ---------------- prepack weights (conv/up/mlp B-fragments, bf16)
__global__ __launch_bounds__(256) void k_repackb(const float* __restrict__ Wc1, const float* __restrict__ Wc2,
        const float* __restrict__ Wup, const float* __restrict__ Wmlp,
        short* __restrict__ wb1, short* __restrict__ wb2, short* __restrict__ wupb, short* __restrict__ wmb) {
  int i = blockIdx.x*256 + threadIdx.x;
  if (i < 27648) {
    int cc = i / 9216, r = i % 9216;
    int tap = r / 1024, r2 = r % 1024;
    int nt = r2 >> 9, lane = (r2 >> 3) & 63, j = r2 & 7;
    int o = nt*16 + (lane & 15);
    int cin = cc*32 + (lane >> 4)*8 + j;
    wb1[i] = f2bf(Wc1[(o*96 + cin)*9 + tap]);
  }
  if (i < 9216) {
    int tap = i / 1024, r2 = i % 1024;
    int nt = r2 >> 9, lane = (r2 >> 3) & 63, j = r2 & 7;
    int o = nt*16 + (lane & 15);
    int cin = (lane >> 4)*8 + j;
    wb2[i] = f2bf(Wc2[(o*32 + cin)*9 + tap]);
  }
  if (i < 16384) {
    int j = i & 7, lane = (i >> 3) & 63, r = i >> 9;
    int nt = r & 3, kb = (r >> 2) & 1, p = r >> 3;
    int c = kb*32 + (lane >> 4)*8 + j;
    int o = nt*16 + (lane & 15);
    wupb[i] = f2bf(Wup[(c*64 + o)*4 + p]);
  }
  if (i < 4096) {
    // wmb[(ck*2+nt)*512 + lane*8 + j] = Wmlp[k = ck*32+(lane>>4)*8+j][o = nt*16+(lane&15)]
    int j = i & 7, lane = (i >> 3) & 63, nt = (i >> 9) & 1, ck = i >> 10;
    int k = ck*32 + (lane >> 4)*8 + j;
    int o = nt*16 + (lane & 15);
    wmb[i] = f2bf(Wmlp[k*32 + o]);
  }
}

// ---------------- x2 fp32 planar [b][c][s][pos] -> bf16 CL [b][s][pos][c]
__global__ __launch_bounds__(256) void k_x2t(const float* __restrict__ x2, short* __restrict__ x2t) {
  __shared__ short lds[32*264];
  int s = blockIdx.y, b = blockIdx.z;
  int tile = blockIdx.x;
  int tid = threadIdx.x;
  #pragma unroll
  for (int k=0; k<8; ++k) {
    int f4 = k*256 + tid;
    int c = f4 >> 6, p4 = f4 & 63;
    float4 v = *(const float4*)(x2 + ((long)(b*32+c)*8 + s)*16384 + tile*256 + p4*4);
    short4v o;
    o[0]=f2bf(v.x); o[1]=f2bf(v.y); o[2]=f2bf(v.z); o[3]=f2bf(v.w);
    *(short4v*)(lds + c*264 + p4*4) = o;
  }
  __syncthreads();
  short* dst = x2t + (((long)(b*8+s)*16384) + tile*256 + tid)*32;
  #pragma unroll
  for (int g=0; g<4; ++g) {
    short8 v;
    #pragma unroll
    for (int j=0; j<8; ++j) v[j] = lds[(g*8+j)*264 + tid];
    *(short8*)(dst + g*8) = v;
  }
}

// ---------------- upsample via MFMA
__global__ __launch_bounds__(256) void k_up_mfma(const float* __restrict__ x1,
        const short* __restrict__ wupb, const float* __restrict__ bup,
        short* __restrict__ Ub) {
  __shared__ __align__(16) char smem[34816];
  short8* stage = (short8*)smem;
  int t = blockIdx.y, b = blockIdx.z;
  int chunk = blockIdx.x >> 2, parity = blockIdx.x & 3;
  int tid = threadIdx.x, lane = tid & 63, w = tid >> 6;

  {
    const float* xp = x1 + ((long)(b*64)*8 + t)*4096 + chunk*256 + tid;
    #pragma unroll
    for (int o8 = 0; o8 < 8; ++o8) {
      short8 v;
      #pragma unroll
      for (int j = 0; j < 8; ++j) v[j] = f2bf(xp[(long)(o8*8+j)*32768]);
      int kb = o8 >> 2, cq = o8 & 3;
      stage[(kb*16 + (tid>>4))*64 + cq*16 + (tid&15)] = v;
    }
  }
  __syncthreads();

  floatx4 acc[4][4];
  #pragma unroll
  for (int nt=0; nt<4; ++nt) {
    float bb = bup[nt*16 + (lane&15)];
    #pragma unroll
    for (int mt=0; mt<4; ++mt) acc[mt][nt] = (floatx4){bb,bb,bb,bb};
  }
  const short8* wp = (const short8*)wupb;
  #pragma unroll
  for (int kb=0; kb<2; ++kb) {
    short8 bfr[4];
    #pragma unroll
    for (int nt=0; nt<4; ++nt) bfr[nt] = wp[((parity*2+kb)*4+nt)*64 + lane];
    #pragma unroll
    for (int mt=0; mt<4; ++mt) {
      short8 a = stage[(kb*16 + w*4 + mt)*64 + lane];
      #pragma unroll
      for (int nt=0; nt<4; ++nt)
        acc[mt][nt] = __builtin_amdgcn_mfma_f32_16x16x32_bf16(a, bfr[nt], acc[mt][nt], 0,0,0);
    }
  }

  __syncthreads();
  short* trb = (short*)smem;
  #pragma unroll
  for (int mt=0; mt<4; ++mt)
    #pragma unroll
    for (int nt=0; nt<4; ++nt)
      #pragma unroll
      for (int r=0; r<4; ++r)
        trb[(w*64 + mt*16 + (lane>>4)*4 + r)*68 + nt*16 + (lane&15)] = f2bf(acc[mt][nt][r]);
  __syncthreads();

  int ip = chunk*256 + tid;
  int X = 2*(ip>>6) + (parity>>1), Y = 2*(ip&63) + (parity&1);
  short* dst = Ub + (((long)(b*8+t)*16384 + X*128 + Y)*64);
  const short* src = trb + tid*68;
  #pragma unroll
  for (int k=0; k<16; ++k)
    *(short4v*)(dst + k*4) = *(const short4v*)(src + k*4);
}

// ---------------- attn bilinear ctx (VALU) + 128->32 MLP (MFMA) -> HM raw bf16 CL + fused stats
__global__ __launch_bounds__(256) void k_ctxmlp(const short* __restrict__ x2t,
        const float* __restrict__ attn, const short* __restrict__ wmb,
        const float* __restrict__ bmlp, short* __restrict__ HMb, float* __restrict__ st) {
  __shared__ float la[2048];                  // attn [n][slot4][iy16][s8]
  __shared__ __align__(16) short ctxs[256*40]; // A-frag staging / epilogue transpose
  __shared__ float sb[64];
  int t = blockIdx.y, b = blockIdx.z;
  int tid = threadIdx.x, lane = tid & 63, w = tid >> 6;
  int m = lane & 15, kg = lane >> 4;
  int pos = blockIdx.x*256 + tid;
  if (tid < 64) sb[tid] = 0.f;

  int x0 = blockIdx.x*2;
  int ixbase = max((int)floorf((x0+0.5f)*0.125f - 0.5f), 0);

  float4* la4 = (float4*)la;
  const float4* g4 = (const float4*)attn;
  #pragma unroll
  for (int k=0;k<2;++k) {
    int f = k*256 + tid;                      // (n, slot, iy, s4)
    int s4 = f & 1, iy = (f>>1)&15, slot = (f>>5)&3, n = f>>7;
    int ixs = min(ixbase + slot, 15);
    la4[f] = g4[((((n*2+b)*16+ixs)*16+iy)*8+t)*2 + s4];
  }
  __syncthreads();

  int x = pos >> 7, y = pos & 127;
  float ux = (x+0.5f)*0.125f - 0.5f;
  float uy = (y+0.5f)*0.125f - 0.5f;
  int ix0 = (int)floorf(ux), iy0 = (int)floorf(uy);
  float fx = ux - (float)ix0, fy = uy - (float)iy0;
  int sa  = max(ix0,0) - ixbase;
  int sbl = min(ix0+1,15) - ixbase;
  int iya = max(iy0,0), iyb = min(iy0+1,15);
  float w00=(1.f-fx)*(1.f-fy), w01=(1.f-fx)*fy, w10=fx*(1.f-fy), w11=fx*fy;
  float a[4][8];
  #pragma unroll
  for (int n=0;n<4;++n) {
    const float4* p00 = la4 + ((n*4+sa )*16+iya)*2;
    const float4* p01 = la4 + ((n*4+sa )*16+iyb)*2;
    const float4* p10 = la4 + ((n*4+sbl)*16+iya)*2;
    const float4* p11 = la4 + ((n*4+sbl)*16+iyb)*2;
    #pragma unroll
    for (int q=0;q<2;++q) {
      float4 c00=p00[q], c01=p01[q], c10=p10[q], c11=p11[q];
      a[n][q*4+0] = w00*c00.x + w01*c01.x + w10*c10.x + w11*c11.x;
      a[n][q*4+1] = w00*c00.y + w01*c01.y + w10*c10.y + w11*c11.y;
      a[n][q*4+2] = w00*c00.z + w01*c01.z + w10*c10.z + w11*c11.z;
      a[n][q*4+3] = w00*c00.w + w01*c01.w + w10*c10.w + w11*c11.w;
    }
  }

  float b0v = bmlp[m], b1v = bmlp[16+m];
  floatx4 acc[4][2];
  #pragma unroll
  for (int mt=0; mt<4; ++mt) {
    acc[mt][0] = (floatx4){b0v,b0v,b0v,b0v};
    acc[mt][1] = (floatx4){b1v,b1v,b1v,b1v};
  }

  const short8* wm = (const short8*)wmb;
  for (int ck=0; ck<4; ++ck) {
    // load 8 channels (ck*8..) for all 8 s, this position
    short8 xr[8];
    #pragma unroll
    for (int s=0;s<8;++s)
      xr[s] = *(const short8*)(x2t + (((long)(b*8+s)*16384) + pos)*32 + ck*8);
    float ctx[8][4];
    #pragma unroll
    for (int c=0;c<8;++c) { ctx[c][0]=0.f; ctx[c][1]=0.f; ctx[c][2]=0.f; ctx[c][3]=0.f; }
    #pragma unroll
    for (int s=0;s<8;++s) {
      float xv[8];
      #pragma unroll
      for (int c=0;c<8;++c) xv[c] = bf2f(xr[s][c]);
      #pragma unroll
      for (int n=0;n<4;++n) {
        float an = a[n][s];
        #pragma unroll
        for (int c=0;c<8;++c) ctx[c][n] = fmaf(an, xv[c], ctx[c][n]);
      }
    }
    // pack to A-frag staging: k-local = c*4+n
    #pragma unroll
    for (int g=0; g<4; ++g) {
      short8 v;
      #pragma unroll
      for (int j=0;j<8;++j) { int kl = g*8+j; v[j] = f2bf(ctx[kl>>2][kl&3]); }
      *(short8*)(ctxs + tid*40 + g*8) = v;
    }
    __syncthreads();
    short8 wb0 = wm[(ck*2+0)*64 + lane];
    short8 wb1f = wm[(ck*2+1)*64 + lane];
    #pragma unroll
    for (int mt=0; mt<4; ++mt) {
      short8 af = *(const short8*)(ctxs + ((w*4+mt)*16 + m)*40 + kg*8);
      acc[mt][0] = __builtin_amdgcn_mfma_f32_16x16x32_bf16(af, wb0,  acc[mt][0], 0,0,0);
      acc[mt][1] = __builtin_amdgcn_mfma_f32_16x16x32_bf16(af, wb1f, acc[mt][1], 0,0,0);
    }
    __syncthreads();
  }

  // fused per-channel stats from acc
  float s0=0.f,q0=0.f,s1=0.f,q1=0.f;
  #pragma unroll
  for (int mt=0; mt<4; ++mt)
    #pragma unroll
    for (int r=0; r<4; ++r) {
      float v0 = acc[mt][0][r]; s0 += v0; q0 += v0*v0;
      float v1 = acc[mt][1][r]; s1 += v1; q1 += v1*v1;
    }
  s0 += __shfl_xor(s0,16); s0 += __shfl_xor(s0,32);
  q0 += __shfl_xor(q0,16); q0 += __shfl_xor(q0,32);
  s1 += __shfl_xor(s1,16); s1 += __shfl_xor(s1,32);
  q1 += __shfl_xor(q1,16); q1 += __shfl_xor(q1,32);
  if (lane < 16) {
    atomicAdd(&sb[lane],    s0); atomicAdd(&sb[16+lane], s1);
    atomicAdd(&sb[32+lane], q0); atomicAdd(&sb[48+lane], q1);
  }

  // transpose to [pos][ch] bf16, coalesced CL store
  short* tr = ctxs;
  #pragma unroll
  for (int mt=0; mt<4; ++mt) {
    int tile = w*4 + mt;
    #pragma unroll
    for (int nt=0; nt<2; ++nt)
      #pragma unroll
      for (int r=0; r<4; ++r)
        tr[(tile*16 + kg*4 + r)*32 + nt*16 + m] = f2bf(acc[mt][nt][r]);
  }
  __syncthreads();
  long slab = (long)(b*8+t)*16384;
  short8* d8 = (short8*)(HMb + (slab + blockIdx.x*256 + tid)*32);
  const short8* s8 = (const short8*)(tr + tid*32);
  d8[0]=s8[0]; d8[1]=s8[1]; d8[2]=s8[2]; d8[3]=s8[3];
  if (tid < 64) atomicAdd(&st[tid], sb[tid]);
}

__global__ void k_finalize(const float* __restrict__ st, const float* __restrict__ g,
                           const float* __restrict__ be, float* __restrict__ sc, float* __restrict__ sh) {
  int c = threadIdx.x;
  if (c < 32) {
    float mean = st[c] * (1.f/262144.f);
    float var  = st[32+c] * (1.f/262144.f) - mean*mean;
    float s = g[c] / sqrtf(var + EPSV);
    sc[c] = s;
    sh[c] = be[c] - mean*s;
  }
}

// ---------------- 3x3 conv via bf16 MFMA implicit GEMM, reg->LDS double-buffered K-chunks.
template<int NCHUNK>
__global__ __launch_bounds__(256) void k_convp(
    const short* __restrict__ src0, const short* __restrict__ srcU,
    const short* __restrict__ wb, const float* __restrict__ bias,
    const float* __restrict__ sc, const float* __restrict__ sh,
    short* __restrict__ dstCL, float* __restrict__ st) {
  constexpr int NBUF = (NCHUNK > 1) ? 2 : 1;
  __shared__ __align__(16) short stage[NBUF][324*40];
  __shared__ float sbuf[64];
  int t = blockIdx.y, b = blockIdx.z;
  int tid = threadIdx.x, lane = tid & 63, w = tid >> 6;
  if (tid < 64) sbuf[tid] = 0.f;
  long slab = (long)(b*8+t)*16384;
  int x0 = (int)(blockIdx.x >> 3) * 16, y0 = (int)(blockIdx.x & 7) * 16;
  int m = lane & 15, kg = lane >> 4;

  int pA = tid;        int rA = pA/18, cA = pA - rA*18;
  int XA = x0-1+rA, YA = y0-1+cA;
  bool okA = ((unsigned)XA < 128u) & ((unsigned)YA < 128u);
  int pB = tid + 256;  bool hasB = pB < 324;
  int rB = pB/18, cB = pB - rB*18;
  int XB = x0-1+rB, YB = y0-1+cB;
  bool okB = hasB && (((unsigned)XB < 128u) & ((unsigned)YB < 128u));
  long offA = slab + XA*128 + YA, offB = slab + XB*128 + YB;

  short8 preA[4], preB[4];

  float bias0 = bias[m], bias1 = bias[16 + m];
  floatx4 acc[4][2];
  #pragma unroll
  for (int mt=0; mt<4; ++mt) {
    acc[mt][0] = (floatx4){bias0,bias0,bias0,bias0};
    acc[mt][1] = (floatx4){bias1,bias1,bias1,bias1};
  }

  {
    const short* sA = src0 + offA*32;
    const short* sB = src0 + offB*32;
    #pragma unroll
    for (int g=0; g<4; ++g) {
      preA[g] = okA ? *(const short8*)(sA + g*8) : (short8)0;
      preB[g] = okB ? *(const short8*)(sB + g*8) : (short8)0;
    }
  }
  #pragma unroll
  for (int g=0; g<4; ++g) {
    short8 vA, vB;
    #pragma unroll
    for (int j=0;j<8;++j) {
      int ch = g*8+j;
      float scv = sc[ch], shv = sh[ch];
      vA[j] = okA ? f2bf(fmaxf(fmaf(bf2f(preA[g][j]), scv, shv), 0.f)) : (short)0;
      vB[j] = okB ? f2bf(fmaxf(fmaf(bf2f(preB[g][j]), scv, shv), 0.f)) : (short)0;
    }
    *(short8*)(&stage[0][pA*40 + g*8]) = vA;
    if (hasB) *(short8*)(&stage[0][pB*40 + g*8]) = vB;
  }
  __syncthreads();

  const short8* wbp = (const short8*)wb;
  #pragma unroll
  for (int cc=0; cc<NCHUNK; ++cc) {
    if (cc+1 < NCHUNK) {
      int coff = cc*32;
      const short* sA = srcU + offA*64 + coff;
      const short* sB = srcU + offB*64 + coff;
      #pragma unroll
      for (int g=0; g<4; ++g) {
        preA[g] = okA ? *(const short8*)(sA + g*8) : (short8)0;
        preB[g] = okB ? *(const short8*)(sB + g*8) : (short8)0;
      }
    }
    #pragma unroll
    for (int tap=0; tap<9; ++tap) {
      int dy = tap/3, dx = tap - 3*dy;
      short8 b0 = wbp[((cc*9+tap)*2+0)*64 + lane];
      short8 b1 = wbp[((cc*9+tap)*2+1)*64 + lane];
      #pragma unroll
      for (int mt=0; mt<4; ++mt) {
        int p = (w*4 + mt + dy)*18 + m + dx;
        short8 a = *(const short8*)(&stage[cc & (NBUF-1)][p*40 + kg*8]);
        acc[mt][0] = __builtin_amdgcn_mfma_f32_16x16x32_bf16(a, b0, acc[mt][0], 0,0,0);
        acc[mt][1] = __builtin_amdgcn_mfma_f32_16x16x32_bf16(a, b1, acc[mt][1], 0,0,0);
      }
    }
    if (cc+1 < NCHUNK) {
      #pragma unroll
      for (int g=0; g<4; ++g) {
        *(short8*)(&stage[(cc+1) & (NBUF-1)][pA*40 + g*8]) = preA[g];
        if (hasB) *(short8*)(&stage[(cc+1) & (NBUF-1)][pB*40 + g*8]) = preB[g];
      }
    }
    __syncthreads();
  }

  float s0=0.f,q0=0.f,s1=0.f,q1=0.f;
  #pragma unroll
  for (int mt=0; mt<4; ++mt)
    #pragma unroll
    for (int r=0; r<4; ++r) {
      float v0 = acc[mt][0][r]; s0 += v0; q0 += v0*v0;
      float v1 = acc[mt][1][r]; s1 += v1; q1 += v1*v1;
    }
  s0 += __shfl_xor(s0,16); s0 += __shfl_xor(s0,32);
  q0 += __shfl_xor(q0,16); q0 += __shfl_xor(q0,32);
  s1 += __shfl_xor(s1,16); s1 += __shfl_xor(s1,32);
  q1 += __shfl_xor(q1,16); q1 += __shfl_xor(q1,32);
  if (lane < 16) {
    atomicAdd(&sbuf[lane],    s0); atomicAdd(&sbuf[16+lane], s1);
    atomicAdd(&sbuf[32+lane], q0); atomicAdd(&sbuf[48+lane], q1);
  }

  short* tr = &stage[0][0];
  #pragma unroll
  for (int mt=0; mt<4; ++mt) {
    int tile = w*4 + mt;
    #pragma unroll
    for (int nt=0; nt<2; ++nt)
      #pragma unroll
      for (int r=0; r<4; ++r)
        tr[(tile*16 + kg*4 + r)*32 + nt*16 + m] = f2bf(acc[mt][nt][r]);
  }
  __syncthreads();
  int px = tid >> 4, py = tid & 15;
  short8* d8 = (short8*)(dstCL + ((slab + (long)(x0+px)*128 + (y0+py))*32));
  const short8* s8 = (const short8*)(tr + tid*32);
  d8[0]=s8[0]; d8[1]=s8[1]; d8[2]=s8[2]; d8[3]=s8[3];
  if (tid < 64) atomicAdd(&st[tid], sbuf[tid]);
}

// ---------------- final BN+ReLU: C2b (bf16 CL) -> out (fp32 planar)
__global__ __launch_bounds__(256) void k_bnrelu2(const short* __restrict__ C2b,
        const float* __restrict__ sc, const float* __restrict__ sh,
        float* __restrict__ out) {
  __shared__ float tb[10592];
  int t = blockIdx.y, b = blockIdx.z;
  int posbase = blockIdx.x * 256;
  int tid = threadIdx.x;
  long slab = (long)(b*8+t)*16384;
  {
    const short8* sp = (const short8*)(C2b + (slab + posbase + tid)*32);
    int pi = tid + (tid>>5)*8;
    #pragma unroll
    for (int g=0; g<4; ++g) {
      short8 v = sp[g];
      #pragma unroll
      for (int j=0; j<8; ++j) {
        int ch = g*8+j;
        tb[ch*321 + pi] = fmaxf(fmaf(bf2f(v[j]), sc[ch], sh[ch]), 0.f);
      }
    }
  }
  __syncthreads();
  int ch = tid >> 3, pg = tid & 7;
  float* op = out + ((long)(b*32+ch)*8 + t)*16384 + posbase + pg*32;
  const float* tp = tb + ch*321 + pg*40;
  #pragma unroll
  for (int k=0; k<8; ++k) {
    float4 v;
    v.x = tp[k*4+0]; v.y = tp[k*4+1]; v.z = tp[k*4+2]; v.w = tp[k*4+3];
    *(float4*)(op + k*4) = v;
  }
}

extern "C" void kernel_launch(void* const* d_in, const int* in_sizes, int n_in,
                              void* d_out, int out_size, void* d_ws, size_t ws_size,
                              hipStream_t stream) {
  (void)in_sizes; (void)n_in; (void)out_size; (void)ws_size;
  const float* x1   = (const float*)d_in[0];
  const float* x2   = (const float*)d_in[1];
  const float* attn = (const float*)d_in[2];
  const float* Wup  = (const float*)d_in[3];
  const float* bup  = (const float*)d_in[4];
  const float* Wmlp = (const float*)d_in[5];
  const float* bmlp = (const float*)d_in[6];
  const float* gmlp = (const float*)d_in[7];
  const float* bemlp= (const float*)d_in[8];
  const float* Wc1  = (const float*)d_in[9];
  const float* bc1  = (const float*)d_in[10];
  const float* gc1  = (const float*)d_in[11];
  const float* bec1 = (const float*)d_in[12];
  const float* Wc2  = (const float*)d_in[13];
  const float* bc2  = (const float*)d_in[14];
  const float* gc2  = (const float*)d_in[15];
  const float* bec2 = (const float*)d_in[16];
  float* ws  = (float*)d_ws;
  float* out = (float*)d_out;

  short* Ub   = (short*)(ws + UB_OFF);
  short* HMb  = (short*)(ws + HMB_OFF);
  short* C1b  = (short*)(ws + C1B_OFF);
  short* C2b  = (short*)(ws + C2B_OFF);
  short* x2t  = (short*)(ws + X2T_OFF);
  short* wb1  = (short*)(ws + WB1_OFF);
  short* wb2  = (short*)(ws + WB2_OFF);
  short* wupb = (short*)(ws + WUP_OFF);
  short* wmb  = (short*)(ws + WMB_OFF);
  float* st1  = ws + ST_OFF;
  float* st2  = st1 + 64;
  float* st3  = st2 + 64;
  float* sc1  = ws + SC_OFF;  float* sh1 = sc1+32;
  float* sc2  = sh1+32;       float* sh2 = sc2+32;
  float* sc3  = sh2+32;       float* sh3 = sc3+32;

  hipMemsetAsync(st1, 0, 192*sizeof(float), stream);
  k_repackb<<<108, 256, 0, stream>>>(Wc1, Wc2, Wup, Wmlp, wb1, wb2, wupb, wmb);
  k_x2t<<<dim3(64,8,2), 256, 0, stream>>>(x2, x2t);
  k_up_mfma<<<dim3(64,8,2), 256, 0, stream>>>(x1, wupb, bup, Ub);
  k_ctxmlp<<<dim3(64,8,2), 256, 0, stream>>>(x2t, attn, wmb, bmlp, HMb, st1);
  k_finalize<<<1, 32, 0, stream>>>(st1, gmlp, bemlp, sc1, sh1);
  k_convp<3><<<dim3(64,8,2), 256, 0, stream>>>(HMb, Ub, wb1, bc1, sc1, sh1, C1b, st2);
  k_finalize<<<1, 32, 0, stream>>>(st2, gc1, bec1, sc2, sh2);
  k_convp<1><<<dim3(64,8,2), 256, 0, stream>>>(C1b, nullptr, wb2, bc2, sc2, sh2, C2b, st3);
  k_finalize<<<1, 32, 0, stream>>>(st3, gc2, bec2, sc3, sh3);
  k_bnrelu2<<<dim3(64,8,2), 256, 0, stream>>>(C2b, sc3, sh3, out);
}